// Round 8
// baseline (272.060 us; speedup 1.0000x reference)
//
#include <hip/hip_runtime.h>

#define H 512
#define NTOK 64
#define NPIX 49
#define CDIM 2048
#define VOCAB 10000

// ws layout (float offsets). NO region requires zero-init (all plain-stored).
#define WS_S      0         // 64x512
#define WS_ST     32768     // 512x64
#define WS_HT     65536     // 512x64
#define WS_XT     98304     // 512x64
#define WS_HPT    131072    // 512x64
#define WS_FM     163840    // 8x2048
#define WS_G2F    180224    // 64x512 reduced G2
#define WS_P1     212992    // 8 kc x 64 n x 64  (h@Wg partials)
#define WS_P2     245760    // 8 kc x 64 n x 64  (s@Ws partials)
#define WS_CCH    278528    // 16 kc x 64 n x 52 (cchan partials)
#define WS_A0     331776    // 64x2048 cxt/alpha0; CSPT / CHT alias after death
#define WS_CSPT   331776
#define WS_CHT    331776
#define WS_BIG    462848    // time-shared slab window (10.2 MB):
//   phase1: sg2 slabs   48 x 32768   (st*16+kc)
//   phase2: M slabs     16 x 153664  (s*64*2401)
//   phase3: gsp slabs   64 x 32768   (st*8+kc)
//   phase4: score slabs  4 x 640000
#define WS_MF     3022848   // 64 x 2401 reduced M
// end = 3176512 floats ~= 12.7 MB

#define OUT_ALPHA 640000
#define OUT_BETA  643136

__device__ __forceinline__ float rcp_fast(float x) {
#if __has_builtin(__builtin_amdgcn_rcpf)
  return __builtin_amdgcn_rcpf(x);
#else
  return 1.0f / x;
#endif
}
__device__ __forceinline__ float tanh_f(float x) {
  float e = __expf(2.0f * x);
  return 1.0f - 2.0f * rcp_fast(e + 1.0f);
}
__device__ __forceinline__ float sigmoid_f(float x) {
  return rcp_fast(1.0f + __expf(-x));
}

// prep: featmean (64 blocks) + transposes x/h/hprev (384 blocks)
__global__ __launch_bounds__(256) void k_prep(const float* __restrict__ x,
    const float* __restrict__ hid, const float* __restrict__ V,
    float* __restrict__ ws) {
  int bid = blockIdx.x, tid = threadIdx.x;
  if (bid < 64) {
    int b = bid >> 3, c = (bid & 7) * 256 + tid;
    float s = 0.0f;
    for (int k = 0; k < NPIX; ++k) s += V[b * NPIX * CDIM + k * CDIM + c];
    ws[WS_FM + b * CDIM + c] = s * (1.0f / NPIX);
  } else {
    int i3 = (bid - 64) * 256 + tid;
    int role = i3 >> 15, idx = i3 & 32767;
    int n = idx >> 9, k = idx & 511;
    if (role == 0)      ws[WS_XT + k * 64 + n] = x[idx];
    else if (role == 1) ws[WS_HT + k * 64 + n] = hid[idx];
    else                ws[WS_HPT + k * 64 + n] = (n & 7) ? hid[idx - 512] : 0.0f;
  }
}

// partial-slab gemm: Cslab[(n0+j)*512+c] = sum_{k0..k0+nk} A^T[k][n0+j] * W[k*512+c]
__device__ __forceinline__ void gemm16s(const float* __restrict__ A,
    const float* __restrict__ W, float* __restrict__ Cslab,
    int n0, int k0, int nk, int c) {
  float acc[16];
#pragma unroll
  for (int j = 0; j < 16; ++j) acc[j] = 0.0f;
#pragma unroll 4
  for (int kk = 0; kk < nk; ++kk) {
    int k = k0 + kk;
    float w = W[k * 512 + c];
    const float4* A4 = (const float4*)(A + k * 64 + n0);
#pragma unroll
    for (int q = 0; q < 4; ++q) {
      float4 a = A4[q];
      acc[q * 4 + 0] += a.x * w;
      acc[q * 4 + 1] += a.y * w;
      acc[q * 4 + 2] += a.z * w;
      acc[q * 4 + 3] += a.w * w;
    }
  }
#pragma unroll
  for (int j = 0; j < 16; ++j) Cslab[(n0 + j) * 512 + c] = acc[j];
}

// streams 0:(XT,Wsx) 1:(HPT,Wsh) 2:(HT,Wg2) -> slabs st*16+kc ; grid (2,16,12)
__global__ __launch_bounds__(256) void k_gemm_sg2(const float* __restrict__ Wsx,
    const float* __restrict__ Wsh, const float* __restrict__ Wg2,
    float* __restrict__ ws) {
  int c = blockIdx.x * 256 + threadIdx.x;
  int kc = blockIdx.y;
  int z = blockIdx.z, st = z >> 2, n0 = (z & 3) * 16;
  const float* A = (st == 0) ? ws + WS_XT : (st == 1) ? ws + WS_HPT : ws + WS_HT;
  const float* W = (st == 0) ? Wsx : (st == 1) ? Wsh : Wg2;
  float* C = ws + WS_BIG + (st * 16 + kc) * 32768;
  gemm16s(A, W, C, n0, kc * 32, 32, c);
}

// reduce slabs: S = sigmoid(sum slabs 0..31)*tanh(cells) -> S,ST ; G2F = sum slabs 32..47
__global__ __launch_bounds__(256) void k_act_s(const float* __restrict__ cells,
    float* __restrict__ ws) {
  int idx = blockIdx.x * 256 + threadIdx.x;
  int n = idx >> 9, c = idx & 511;
  float sa = 0.0f, g = 0.0f;
#pragma unroll
  for (int s = 0; s < 32; ++s) sa += ws[WS_BIG + s * 32768 + idx];
#pragma unroll
  for (int s = 32; s < 48; ++s) g += ws[WS_BIG + s * 32768 + idx];
  float v = sigmoid_f(sa) * tanh_f(cells[idx]);
  ws[WS_S + idx] = v;
  ws[WS_ST + c * 64 + n] = v;
  ws[WS_G2F + idx] = g;
}

// cxt[n][c] = sum_j tanh(fm[b][c]*Wfeat[j] + g2[n][j]) * Wcxt[j]
__global__ __launch_bounds__(256) void k_cxt(const float* __restrict__ Wfeat,
    const float* __restrict__ Wcxt, float* __restrict__ ws) {
  __shared__ float2 fw[512];
  __shared__ float g2l[512];
  int tid = threadIdx.x, n = blockIdx.y, b = n >> 3;
  int c = blockIdx.x * 256 + tid;
  for (int i = tid; i < 512; i += 256) {
    fw[i] = make_float2(Wfeat[i], Wcxt[i]);
    g2l[i] = ws[WS_G2F + n * H + i];
  }
  __syncthreads();
  float fm = ws[WS_FM + b * CDIM + c];
  float acc = 0.0f;
#pragma unroll 4
  for (int j = 0; j < 512; ++j) {
    float2 p = fw[j];
    acc += tanh_f(fm * p.x + g2l[j]) * p.y;
  }
  ws[WS_A0 + n * CDIM + c] = acc;
}

// bid<64: softmax over A0 row. bid>=64: cs_hwg partials (n, half), wave=kc
__global__ __launch_bounds__(256) void k_softmax_cshwg(const float* __restrict__ hid,
    const float* __restrict__ Wg, const float* __restrict__ Ws_,
    float* __restrict__ ws) {
  int bid = blockIdx.x, tid = threadIdx.x;
  if (bid < 64) {
    __shared__ float red[4];
    int n = bid, lane = tid & 63, w = tid >> 6;
    float* row = ws + WS_A0 + n * CDIM;
    float v[8];
    float m = -1e30f;
#pragma unroll
    for (int i = 0; i < 8; ++i) { v[i] = row[tid + i * 256]; m = fmaxf(m, v[i]); }
    for (int off = 32; off; off >>= 1) m = fmaxf(m, __shfl_xor(m, off));
    if (lane == 0) red[w] = m;
    __syncthreads();
    m = fmaxf(fmaxf(red[0], red[1]), fmaxf(red[2], red[3]));
    float s = 0.0f;
#pragma unroll
    for (int i = 0; i < 8; ++i) { v[i] = __expf(v[i] - m); s += v[i]; }
    for (int off = 32; off; off >>= 1) s += __shfl_xor(s, off);
    __syncthreads();
    if (lane == 0) red[w] = s;
    __syncthreads();
    s = red[0] + red[1] + red[2] + red[3];
    float inv = rcp_fast(s);
#pragma unroll
    for (int i = 0; i < 8; ++i) row[tid + i * 256] = v[i] * inv;
  } else {
    int bidx = bid - 64;
    int n = bidx & 63, half = bidx >> 6;
    int k2 = tid & 63, w = tid >> 6;
    int kc = half * 4 + w;
    const float* hrow = hid + n * H;
    const float* srow = ws + WS_S + n * H;
    float a1 = 0.0f, a2 = 0.0f;
#pragma unroll 4
    for (int kk = 0; kk < 64; ++kk) {
      int k = kc * 64 + kk;
      if (k2 < NPIX) {
        a1 += hrow[k] * Wg[k * NPIX + k2];
        a2 += srow[k] * Ws_[k * NPIX + k2];
      }
    }
    if (k2 < NPIX) {
      ws[WS_P1 + (kc * 64 + n) * 64 + k2] = a1;
      ws[WS_P2 + (kc * 64 + n) * 64 + k2] = a2;
    }
  }
}

// attnM: grid (16 cchunk, 64 n). Two 64-c sub-stages (halved LDS -> 6 blocks/CU);
// 4x4 reg tiles; result routed through LDS, plain-stored as linear 2401 partial.
__global__ __launch_bounds__(256) void k_attnM(const float* __restrict__ V,
    const float* __restrict__ Wv, float* __restrict__ ws) {
  __shared__ float vl[64 * 52];
  __shared__ float wl[64 * 52];
  int tid = threadIdx.x;
  int kc = blockIdx.x, n = blockIdx.y, b = n >> 3;
  int c0 = kc * 128;
  const float* a0 = ws + WS_A0 + n * CDIM + c0;
  const float* Vb = V + b * NPIX * CDIM + c0;
  int ti = tid >> 4, tj = tid & 15;
  float acc[4][4];
#pragma unroll
  for (int i = 0; i < 4; ++i)
#pragma unroll
    for (int j = 0; j < 4; ++j) acc[i][j] = 0.0f;
  float cch = 0.0f;
#pragma unroll
  for (int sc = 0; sc < 2; ++sc) {
    int cb = sc * 64;
    __syncthreads();
    for (int idx = tid; idx < NPIX * 64; idx += 256) {
      int k = idx >> 6, cc = idx & 63;
      vl[cc * 52 + k] = a0[cb + cc] * Vb[k * CDIM + cb + cc];
    }
    for (int idx = tid; idx < 64 * 64; idx += 256) {
      int cc = idx >> 6, r = idx & 63;
      if (r < NPIX) wl[cc * 52 + r] = Wv[(c0 + cb + cc) * NPIX + r];
    }
    __syncthreads();
    if (tid < NPIX) {
#pragma unroll 8
      for (int cc = 0; cc < 64; ++cc) cch += vl[cc * 52 + tid];
    }
    if (ti < 13 && tj < 13) {
#pragma unroll 4
      for (int cc = 0; cc < 64; ++cc) {
        float4 a = *(const float4*)&vl[cc * 52 + 4 * ti];
        float4 w = *(const float4*)&wl[cc * 52 + 4 * tj];
        acc[0][0] += a.x * w.x; acc[0][1] += a.x * w.y; acc[0][2] += a.x * w.z; acc[0][3] += a.x * w.w;
        acc[1][0] += a.y * w.x; acc[1][1] += a.y * w.y; acc[1][2] += a.y * w.z; acc[1][3] += a.y * w.w;
        acc[2][0] += a.z * w.x; acc[2][1] += a.z * w.y; acc[2][2] += a.z * w.z; acc[2][3] += a.z * w.w;
        acc[3][0] += a.w * w.x; acc[3][1] += a.w * w.y; acc[3][2] += a.w * w.z; acc[3][3] += a.w * w.w;
      }
    }
  }
  if (tid < NPIX) ws[WS_CCH + (kc * 64 + n) * 52 + tid] = cch * (1.0f / CDIM);
  __syncthreads();          // vl reads done; reuse vl+wl as output tile (2704 >= 2401)
  float* ml = vl;
  if (ti < 13 && tj < 13) {
#pragma unroll
    for (int jj = 0; jj < 4; ++jj) {
      int k2 = 4 * tj + jj;
      if (k2 < NPIX) {
#pragma unroll
        for (int ii = 0; ii < 4; ++ii) {
          int k = 4 * ti + ii;
          if (k < NPIX) ml[k2 * 49 + k] = acc[ii][jj];
        }
      }
    }
  }
  __syncthreads();
  float* Mp = ws + WS_BIG + kc * 153664 + n * 2401;
  for (int idx = tid; idx < 2401; idx += 256) Mp[idx] = ml[idx];
}

// reduce the 16 M slabs -> MF[n][2401] ; grid (10, 64)
__global__ __launch_bounds__(256) void k_redM(float* __restrict__ ws) {
  int n = blockIdx.y;
  int i = blockIdx.x * 256 + threadIdx.x;
  if (i < 2401) {
    float m = 0.0f;
#pragma unroll
    for (int s = 0; s < 16; ++s) m += ws[WS_BIG + s * 153664 + n * 2401 + i];
    ws[WS_MF + n * 2401 + i] = m;
  }
}

// zt: reduce P1/P2; z from single MF slab; alpha, beta
__global__ __launch_bounds__(256) void k_zt(const float* __restrict__ Wh,
    float* __restrict__ ws, float* __restrict__ out) {
  __shared__ float gl[NPIX], cl[NPIX], whl[64];
  __shared__ float zbuf[4][64];
  int n = blockIdx.x, tid = threadIdx.x;
  if (tid < NPIX) {
    float s1 = 0.0f, s2 = 0.0f;
#pragma unroll
    for (int kc = 0; kc < 8; ++kc) {
      s1 += ws[WS_P1 + (kc * 64 + n) * 64 + tid];
      s2 += ws[WS_P2 + (kc * 64 + n) * 64 + tid];
    }
    gl[tid] = s1;
    cl[tid] = s1 + s2;
    whl[tid] = Wh[tid];
  }
  __syncthreads();
  int k = tid & 63, g = tid >> 6;
  float zp = 0.0f;
  if (k < NPIX) {
    int k2e = (g == 3) ? NPIX : (g * 13 + 13);
    const float* Mz = ws + WS_MF + n * 2401;
    for (int k2 = g * 13; k2 < k2e; ++k2) {
      float m = Mz[k2 * 49 + k];
      zp += tanh_f(tanh_f(m + gl[k2])) * whl[k2];
    }
  }
  zbuf[g][k] = zp;
  __syncthreads();
  if (tid < 64) {
    int lane = tid;
    float z = zbuf[0][lane] + zbuf[1][lane] + zbuf[2][lane] + zbuf[3][lane];
    float zm = (lane < NPIX) ? z : -1e30f;
    float m1 = zm;
    for (int off = 32; off; off >>= 1) m1 = fmaxf(m1, __shfl_xor(m1, off));
    float e = (lane < NPIX) ? __expf(z - m1) : 0.0f;
    float S1 = e;
    for (int off = 32; off; off >>= 1) S1 += __shfl_xor(S1, off);
    if (lane < NPIX) out[OUT_ALPHA + n * NPIX + lane] = e * rcp_fast(S1);
    float vz = (lane < NPIX) ? tanh_f(cl[lane]) * whl[lane] : 0.0f;
    for (int off = 32; off; off >>= 1) vz += __shfl_xor(vz, off);
    if (lane == 0) {
      float ze = vz;
      float m2 = fmaxf(m1, ze);
      float S2 = S1 * __expf(m1 - m2) + __expf(ze - m2);
      out[OUT_BETA + n] = __expf(ze - m2) * rcp_fast(S2);
    }
  }
}

// c_spatial^T[d][n] = sum_k alpha_t[n][k] * V[b][k][d]
__global__ __launch_bounds__(256) void k_cspatial(const float* __restrict__ V,
    const float* __restrict__ out, float* __restrict__ ws) {
  __shared__ float al[NPIX];
  int bid = blockIdx.x, tid = threadIdx.x;
  int n = bid & 63, b = n >> 3;
  int d = (bid >> 6) * 256 + tid;
  if (tid < NPIX) al[tid] = out[OUT_ALPHA + n * NPIX + tid];
  __syncthreads();
  float s = 0.0f;
#pragma unroll 7
  for (int k = 0; k < NPIX; ++k) s += al[k] * V[b * NPIX * CDIM + k * CDIM + d];
  ws[WS_CSPT + d * 64 + n] = s;
}

// gates+spat -> slabs st*8+kc ; grid (2,8,32)
// st 0:(ST,Wgvs) 1:(HT,Wghs) 2:(ST,Wgvc) 3:(HT,Wghc) 4..7:(CSPT q, Wspat q)
__global__ __launch_bounds__(256) void k_gemm_gsp(const float* __restrict__ Wgvs,
    const float* __restrict__ Wghs, const float* __restrict__ Wgvc,
    const float* __restrict__ Wghc, const float* __restrict__ Wspat,
    float* __restrict__ ws) {
  int c = blockIdx.x * 256 + threadIdx.x;
  int kc = blockIdx.y;
  int z = blockIdx.z, st = z >> 2, n0 = (z & 3) * 16;
  const float* A;
  const float* W;
  if (st < 4) {
    A = ws + ((st & 1) ? WS_HT : WS_ST);
    W = (st == 0) ? Wgvs : (st == 1) ? Wghs : (st == 2) ? Wgvc : Wghc;
  } else {
    int q = st - 4;
    A = ws + WS_CSPT + q * 32768;
    W = Wspat + q * 262144;
  }
  float* C = ws + WS_BIG + (st * 8 + kc) * 32768;
  gemm16s(A, W, C, n0, kc * 64, 64, c);
}

// chat^T[c][n] = sigmoid(GA1)*SPAT + sigmoid(GA2)*(cchan@Wchan) + h
// reduces gsp slabs (GA1 0..15, GA2 16..31, SPAT 32..63) and 16 cchan slabs
__global__ __launch_bounds__(256) void k_chat(const float* __restrict__ hid,
    const float* __restrict__ Wchan, float* __restrict__ ws) {
  __shared__ float cl[NPIX];
  int tid = threadIdx.x, n = blockIdx.y;
  int c = blockIdx.x * 256 + tid;
  if (tid < NPIX) {
    float s = 0.0f;
#pragma unroll
    for (int kc = 0; kc < 16; ++kc) s += ws[WS_CCH + (kc * 64 + n) * 52 + tid];
    cl[tid] = s;
  }
  __syncthreads();
  float acc = 0.0f;
#pragma unroll 7
  for (int k = 0; k < NPIX; ++k) acc += cl[k] * Wchan[k * H + c];
  int idx = n * H + c;
  float ga1 = 0.0f, ga2 = 0.0f, spat = 0.0f;
#pragma unroll
  for (int s = 0; s < 16; ++s)  ga1 += ws[WS_BIG + s * 32768 + idx];
#pragma unroll
  for (int s = 16; s < 32; ++s) ga2 += ws[WS_BIG + s * 32768 + idx];
#pragma unroll
  for (int s = 32; s < 64; ++s) spat += ws[WS_BIG + s * 32768 + idx];
  float chat = sigmoid_f(ga1) * spat + sigmoid_f(ga2) * acc + hid[idx];
  ws[WS_CHT + c * 64 + n] = chat;
}

// scores partial slabs: grid (20, 4, 4); thread = 2 cols x 16 tokens
__global__ __launch_bounds__(256) void k_gemm_scores(const float* __restrict__ Wmlp,
    float* __restrict__ ws) {
  int tid = threadIdx.x;
  int c0 = blockIdx.x * 512 + tid * 2;
  if (c0 >= VOCAB) return;
  int kc = blockIdx.y, k0 = kc * 128;
  int n0 = blockIdx.z * 16;
  const float* A = ws + WS_CHT;
  const float2* W2 = (const float2*)Wmlp;
  int cw = c0 >> 1;
  float2 acc[16];
#pragma unroll
  for (int j = 0; j < 16; ++j) acc[j] = make_float2(0.f, 0.f);
#pragma unroll 4
  for (int kk = 0; kk < 128; ++kk) {
    int k = k0 + kk;
    float2 w = W2[k * (VOCAB / 2) + cw];
    const float4* A4 = (const float4*)(A + k * 64 + n0);
#pragma unroll
    for (int q = 0; q < 4; ++q) {
      float4 a = A4[q];
      acc[q * 4 + 0].x += a.x * w.x; acc[q * 4 + 0].y += a.x * w.y;
      acc[q * 4 + 1].x += a.y * w.x; acc[q * 4 + 1].y += a.y * w.y;
      acc[q * 4 + 2].x += a.z * w.x; acc[q * 4 + 2].y += a.z * w.y;
      acc[q * 4 + 3].x += a.w * w.x; acc[q * 4 + 3].y += a.w * w.y;
    }
  }
  float* slab = ws + WS_BIG + kc * 640000;
#pragma unroll
  for (int j = 0; j < 16; ++j)
    ((float2*)(slab + (n0 + j) * VOCAB))[cw] = acc[j];
}

// out[n][c] = bmlp[c] + sum of 4 score slabs ; grid (40, 64)
__global__ __launch_bounds__(256) void k_red_scores(const float* __restrict__ bmlp,
    float* __restrict__ ws, float* __restrict__ out) {
  int c = blockIdx.x * 256 + threadIdx.x, n = blockIdx.y;
  if (c >= VOCAB) return;
  int idx = n * VOCAB + c;
  float v = bmlp[c];
#pragma unroll
  for (int s = 0; s < 4; ++s) v += ws[WS_BIG + s * 640000 + idx];
  out[idx] = v;
}

extern "C" void kernel_launch(void* const* d_in, const int* in_sizes, int n_in,
                              void* d_out, int out_size, void* d_ws, size_t ws_size,
                              hipStream_t stream) {
  const float* x     = (const float*)d_in[0];
  const float* hid   = (const float*)d_in[1];
  const float* cells = (const float*)d_in[2];
  const float* V     = (const float*)d_in[3];
  const float* Wsx   = (const float*)d_in[4];
  const float* Wsh   = (const float*)d_in[5];
  const float* Wv    = (const float*)d_in[6];
  const float* Wg    = (const float*)d_in[7];
  const float* Ws_   = (const float*)d_in[8];
  const float* Wh    = (const float*)d_in[9];
  const float* Wfeat = (const float*)d_in[10];
  const float* Wcxt  = (const float*)d_in[11];
  const float* Wg2   = (const float*)d_in[12];
  const float* Wspat = (const float*)d_in[13];
  const float* Wchan = (const float*)d_in[14];
  const float* Wgvs  = (const float*)d_in[15];
  const float* Wgvc  = (const float*)d_in[16];
  const float* Wghs  = (const float*)d_in[17];
  const float* Wghc  = (const float*)d_in[18];
  const float* Wmlp  = (const float*)d_in[19];
  const float* bmlp  = (const float*)d_in[20];
  float* ws  = (float*)d_ws;
  float* out = (float*)d_out;

  hipLaunchKernelGGL(k_prep, dim3(448), dim3(256), 0, stream, x, hid, V, ws);
  hipLaunchKernelGGL(k_gemm_sg2, dim3(2, 16, 12), dim3(256), 0, stream, Wsx, Wsh, Wg2, ws);
  hipLaunchKernelGGL(k_act_s, dim3(128), dim3(256), 0, stream, cells, ws);
  hipLaunchKernelGGL(k_cxt, dim3(8, 64), dim3(256), 0, stream, Wfeat, Wcxt, ws);
  hipLaunchKernelGGL(k_softmax_cshwg, dim3(192), dim3(256), 0, stream, hid, Wg, Ws_, ws);
  hipLaunchKernelGGL(k_attnM, dim3(16, 64), dim3(256), 0, stream, V, Wv, ws);
  hipLaunchKernelGGL(k_redM, dim3(10, 64), dim3(256), 0, stream, ws);
  hipLaunchKernelGGL(k_zt, dim3(64), dim3(256), 0, stream, Wh, ws, out);
  hipLaunchKernelGGL(k_cspatial, dim3(512), dim3(256), 0, stream, V, out, ws);
  hipLaunchKernelGGL(k_gemm_gsp, dim3(2, 8, 32), dim3(256), 0, stream, Wgvs, Wghs, Wgvc, Wghc, Wspat, ws);
  hipLaunchKernelGGL(k_chat, dim3(2, 64), dim3(256), 0, stream, hid, Wchan, ws);
  hipLaunchKernelGGL(k_gemm_scores, dim3(20, 4, 4), dim3(256), 0, stream, Wmlp, ws);
  hipLaunchKernelGGL(k_red_scores, dim3(40, 64), dim3(256), 0, stream, bmlp, ws, out);
}

// Round 9
// 253.969 us; speedup vs baseline: 1.0712x; 1.0712x over previous
//
#include <hip/hip_runtime.h>

#define H 512
#define NTOK 64
#define NPIX 49
#define CDIM 2048
#define VOCAB 10000

// ws layout (float offsets). NO region requires zero-init (all plain-stored).
#define WS_S      0         // 64x512
#define WS_ST     32768     // 512x64
#define WS_HT     65536     // 512x64
#define WS_XT     98304     // 512x64
#define WS_HPT    131072    // 512x64
#define WS_FM     163840    // 8x2048
#define WS_G2F    180224    // 64x512 reduced G2
#define WS_P1     212992    // 8 kc x 64 n x 64  (h@Wg partials)
#define WS_P2     245760    // 8 kc x 64 n x 64  (s@Ws partials)
#define WS_CCH    278528    // 16 kc x 64 n x 52 (cchan partials)
#define WS_A0     331776    // 64x2048 cxt/alpha0; CSPT / CHT alias after death
#define WS_CSPT   331776
#define WS_CHT    331776
// disjoint slab regions (ws is ~268MB; no time-sharing needed)
#define WS_SG2S   462848    // 48 x 32768  sg2 slabs (st*16+kc)
#define WS_GSPS   2035712   // 64 x 32768  gates+spat slabs (st*8+kc)
#define WS_MS     4132864   // 16 x 153664 M partial slabs
#define WS_SCS    6591488   // 4 x 640000  score slabs
#define WS_MF     9151488   // 64 x 2401 reduced M
// end = 9305152 floats ~= 37.2 MB

#define OUT_ALPHA 640000
#define OUT_BETA  643136

typedef __attribute__((ext_vector_type(8))) short short8;
typedef __attribute__((ext_vector_type(4))) float floatx4;

__device__ __forceinline__ float rcp_fast(float x) {
#if __has_builtin(__builtin_amdgcn_rcpf)
  return __builtin_amdgcn_rcpf(x);
#else
  return 1.0f / x;
#endif
}
__device__ __forceinline__ float tanh_f(float x) {
  float e = __expf(2.0f * x);
  return 1.0f - 2.0f * rcp_fast(e + 1.0f);
}
__device__ __forceinline__ float sigmoid_f(float x) {
  return rcp_fast(1.0f + __expf(-x));
}
__device__ __forceinline__ short f2bf(float x) {  // RNE fp32->bf16
  union { float f; unsigned u; } un; un.f = x;
  unsigned r = un.u + 0x7FFFu + ((un.u >> 16) & 1u);
  return (short)(r >> 16);
}
__device__ __forceinline__ float bf2f(unsigned short h) {
  union { unsigned u; float f; } cv; cv.u = ((unsigned)h) << 16;
  return cv.f;
}

// prep: featmean (64 blocks) + transposes x/h/hprev (384 blocks)
__global__ __launch_bounds__(256) void k_prep(const float* __restrict__ x,
    const float* __restrict__ hid, const float* __restrict__ V,
    float* __restrict__ ws) {
  int bid = blockIdx.x, tid = threadIdx.x;
  if (bid < 64) {
    int b = bid >> 3, c = (bid & 7) * 256 + tid;
    float s = 0.0f;
    for (int k = 0; k < NPIX; ++k) s += V[b * NPIX * CDIM + k * CDIM + c];
    ws[WS_FM + b * CDIM + c] = s * (1.0f / NPIX);
  } else {
    int i3 = (bid - 64) * 256 + tid;
    int role = i3 >> 15, idx = i3 & 32767;
    int n = idx >> 9, k = idx & 511;
    if (role == 0)      ws[WS_XT + k * 64 + n] = x[idx];
    else if (role == 1) ws[WS_HT + k * 64 + n] = hid[idx];
    else                ws[WS_HPT + k * 64 + n] = (n & 7) ? hid[idx - 512] : 0.0f;
  }
}

// partial-slab gemm: Cslab[(n0+j)*512+c] = sum_{k0..k0+nk} A^T[k][n0+j] * W[k*512+c]
__device__ __forceinline__ void gemm16s(const float* __restrict__ A,
    const float* __restrict__ W, float* __restrict__ Cslab,
    int n0, int k0, int nk, int c) {
  float acc[16];
#pragma unroll
  for (int j = 0; j < 16; ++j) acc[j] = 0.0f;
#pragma unroll 4
  for (int kk = 0; kk < nk; ++kk) {
    int k = k0 + kk;
    float w = W[k * 512 + c];
    const float4* A4 = (const float4*)(A + k * 64 + n0);
#pragma unroll
    for (int q = 0; q < 4; ++q) {
      float4 a = A4[q];
      acc[q * 4 + 0] += a.x * w;
      acc[q * 4 + 1] += a.y * w;
      acc[q * 4 + 2] += a.z * w;
      acc[q * 4 + 3] += a.w * w;
    }
  }
#pragma unroll
  for (int j = 0; j < 16; ++j) Cslab[(n0 + j) * 512 + c] = acc[j];
}

// streams 0:(XT,Wsx) 1:(HPT,Wsh) 2:(HT,Wg2) -> slabs st*16+kc ; grid (2,16,12)
__global__ __launch_bounds__(256) void k_gemm_sg2(const float* __restrict__ Wsx,
    const float* __restrict__ Wsh, const float* __restrict__ Wg2,
    float* __restrict__ ws) {
  int c = blockIdx.x * 256 + threadIdx.x;
  int kc = blockIdx.y;
  int z = blockIdx.z, st = z >> 2, n0 = (z & 3) * 16;
  const float* A = (st == 0) ? ws + WS_XT : (st == 1) ? ws + WS_HPT : ws + WS_HT;
  const float* W = (st == 0) ? Wsx : (st == 1) ? Wsh : Wg2;
  float* C = ws + WS_SG2S + (st * 16 + kc) * 32768;
  gemm16s(A, W, C, n0, kc * 32, 32, c);
}

// reduce slabs: S = sigmoid(sum slabs 0..31)*tanh(cells) -> S,ST ; G2F = sum slabs 32..47
__global__ __launch_bounds__(256) void k_act_s(const float* __restrict__ cells,
    float* __restrict__ ws) {
  int idx = blockIdx.x * 256 + threadIdx.x;
  int n = idx >> 9, c = idx & 511;
  float sa = 0.0f, g = 0.0f;
#pragma unroll
  for (int s = 0; s < 32; ++s) sa += ws[WS_SG2S + s * 32768 + idx];
#pragma unroll
  for (int s = 32; s < 48; ++s) g += ws[WS_SG2S + s * 32768 + idx];
  float v = sigmoid_f(sa) * tanh_f(cells[idx]);
  ws[WS_S + idx] = v;
  ws[WS_ST + c * 64 + n] = v;
  ws[WS_G2F + idx] = g;
}

// bid<512: cxt[n][c] = sum_j tanh(fm[b][c]*Wfeat[j] + g2[n][j]) * Wcxt[j]
// bid>=512: gates GEMMs (independent; ready after act_s) -> WS_GSPS slabs 0..31
__global__ __launch_bounds__(256) void k_cxt_gates(const float* __restrict__ Wfeat,
    const float* __restrict__ Wcxt, const float* __restrict__ Wgvs,
    const float* __restrict__ Wghs, const float* __restrict__ Wgvc,
    const float* __restrict__ Wghc, float* __restrict__ ws) {
  int bid = blockIdx.x, tid = threadIdx.x;
  if (bid < 512) {
    __shared__ float2 fw[512];
    __shared__ float g2l[512];
    int n = bid & 63, b = n >> 3;
    int c = (bid >> 6) * 256 + tid;
    for (int i = tid; i < 512; i += 256) {
      fw[i] = make_float2(Wfeat[i], Wcxt[i]);
      g2l[i] = ws[WS_G2F + n * H + i];
    }
    __syncthreads();
    float fm = ws[WS_FM + b * CDIM + c];
    float acc = 0.0f;
#pragma unroll 4
    for (int j = 0; j < 512; ++j) {
      float2 p = fw[j];
      acc += tanh_f(fm * p.x + g2l[j]) * p.y;
    }
    ws[WS_A0 + n * CDIM + c] = acc;
  } else {
    int gi = bid - 512;                 // 0..255
    int c = (gi & 1) * 256 + tid;
    int rest = gi >> 1;                 // 0..127
    int kc = rest & 7;
    int zz = rest >> 3;                 // 0..15
    int st = zz >> 2, n0 = (zz & 3) * 16;
    const float* A = ws + ((st & 1) ? WS_HT : WS_ST);
    const float* W = (st == 0) ? Wgvs : (st == 1) ? Wghs : (st == 2) ? Wgvc : Wghc;
    float* C = ws + WS_GSPS + (st * 8 + kc) * 32768;
    gemm16s(A, W, C, n0, kc * 64, 64, c);
  }
}

// bid<64: softmax over A0 row. bid>=64: cs_hwg partials (n, half), wave=kc
__global__ __launch_bounds__(256) void k_softmax_cshwg(const float* __restrict__ hid,
    const float* __restrict__ Wg, const float* __restrict__ Ws_,
    float* __restrict__ ws) {
  int bid = blockIdx.x, tid = threadIdx.x;
  if (bid < 64) {
    __shared__ float red[4];
    int n = bid, lane = tid & 63, w = tid >> 6;
    float* row = ws + WS_A0 + n * CDIM;
    float v[8];
    float m = -1e30f;
#pragma unroll
    for (int i = 0; i < 8; ++i) { v[i] = row[tid + i * 256]; m = fmaxf(m, v[i]); }
    for (int off = 32; off; off >>= 1) m = fmaxf(m, __shfl_xor(m, off));
    if (lane == 0) red[w] = m;
    __syncthreads();
    m = fmaxf(fmaxf(red[0], red[1]), fmaxf(red[2], red[3]));
    float s = 0.0f;
#pragma unroll
    for (int i = 0; i < 8; ++i) { v[i] = __expf(v[i] - m); s += v[i]; }
    for (int off = 32; off; off >>= 1) s += __shfl_xor(s, off);
    __syncthreads();
    if (lane == 0) red[w] = s;
    __syncthreads();
    s = red[0] + red[1] + red[2] + red[3];
    float inv = rcp_fast(s);
#pragma unroll
    for (int i = 0; i < 8; ++i) row[tid + i * 256] = v[i] * inv;
  } else {
    int bidx = bid - 64;
    int n = bidx & 63, half = bidx >> 6;
    int k2 = tid & 63, w = tid >> 6;
    int kc = half * 4 + w;
    const float* hrow = hid + n * H;
    const float* srow = ws + WS_S + n * H;
    float a1 = 0.0f, a2 = 0.0f;
#pragma unroll 4
    for (int kk = 0; kk < 64; ++kk) {
      int k = kc * 64 + kk;
      if (k2 < NPIX) {
        a1 += hrow[k] * Wg[k * NPIX + k2];
        a2 += srow[k] * Ws_[k * NPIX + k2];
      }
    }
    if (k2 < NPIX) {
      ws[WS_P1 + (kc * 64 + n) * 64 + k2] = a1;
      ws[WS_P2 + (kc * 64 + n) * 64 + k2] = a2;
    }
  }
}

// attnM via bf16 MFMA. grid 1024 = (16 kc)x(64 n). Per block: 128-c chunk.
// A[k][c] = bf16(alpha0*V), B'[k2][c] = bf16(Wv^T) in LDS (stride 136 bf16).
// Each wave computes one 16-col tile strip of the 64x64-padded 49x49 output.
__global__ __launch_bounds__(256) void k_attnM(const float* __restrict__ V,
    const float* __restrict__ Wv, float* __restrict__ ws) {
  __shared__ __align__(16) short al[64 * 136];
  __shared__ __align__(16) short bl[64 * 136];
  int tid = threadIdx.x, bid = blockIdx.x;
  int kc = bid >> 6, n = bid & 63, b = n >> 3;
  int c0 = kc * 128;
  const float* a0 = ws + WS_A0 + n * CDIM + c0;
  const float* Vb = V + b * NPIX * CDIM + c0;
  {
    int cc = tid & 127;
    float a0c = a0[cc];
    for (int k = tid >> 7; k < NPIX; k += 2)
      al[k * 136 + cc] = f2bf(a0c * Vb[k * CDIM + cc]);
  }
  for (int idx = tid; idx < 128 * 64; idx += 256) {
    int cc = idx >> 6, r = idx & 63;
    if (r < NPIX) bl[r * 136 + cc] = f2bf(Wv[(c0 + cc) * NPIX + r]);
  }
  __syncthreads();
  // cchan partial (sum over cc of A row)
  if (tid < NPIX) {
    float cch = 0.0f;
    const unsigned short* ar = (const unsigned short*)(al + tid * 136);
#pragma unroll 8
    for (int cc = 0; cc < 128; ++cc) cch += bf2f(ar[cc]);
    ws[WS_CCH + (kc * 64 + n) * 52 + tid] = cch * (1.0f / CDIM);
  }
  int lane = tid & 63, w = tid >> 6;
  int qm = lane >> 4, mr = lane & 15;
  floatx4 acc[4];
#pragma unroll
  for (int i = 0; i < 4; ++i) acc[i] = (floatx4){0.f, 0.f, 0.f, 0.f};
#pragma unroll
  for (int ks = 0; ks < 4; ++ks) {
    int cb = ks * 32 + qm * 8;
    short8 bf = *(const short8*)&bl[(w * 16 + mr) * 136 + cb];
#pragma unroll
    for (int i = 0; i < 4; ++i) {
      short8 af = *(const short8*)&al[(i * 16 + mr) * 136 + cb];
      acc[i] = __builtin_amdgcn_mfma_f32_16x16x32_bf16(af, bf, acc[i], 0, 0, 0);
    }
  }
  __syncthreads();           // all MFMA LDS reads done; reuse al as fp32 out tile
  float* ml = (float*)al;    // 2401 floats (9.6KB) fits in al (17.4KB)
  int k2 = w * 16 + mr;
  if (k2 < NPIX) {
#pragma unroll
    for (int i = 0; i < 4; ++i) {
#pragma unroll
      for (int r = 0; r < 4; ++r) {
        int kp = i * 16 + qm * 4 + r;
        if (kp < NPIX) ml[k2 * 49 + kp] = acc[i][r];
      }
    }
  }
  __syncthreads();
  float* Mp = ws + WS_MS + kc * 153664 + n * 2401;
  for (int idx = tid; idx < 2401; idx += 256) Mp[idx] = ml[idx];
}

// reduce the 16 M slabs -> MF[n][2401] ; grid (10, 64)
__global__ __launch_bounds__(256) void k_redM(float* __restrict__ ws) {
  int n = blockIdx.y;
  int i = blockIdx.x * 256 + threadIdx.x;
  if (i < 2401) {
    float m = 0.0f;
#pragma unroll
    for (int s = 0; s < 16; ++s) m += ws[WS_MS + s * 153664 + n * 2401 + i];
    ws[WS_MF + n * 2401 + i] = m;
  }
}

// zt: reduce P1/P2; z from single MF slab; alpha, beta
__global__ __launch_bounds__(256) void k_zt(const float* __restrict__ Wh,
    float* __restrict__ ws, float* __restrict__ out) {
  __shared__ float gl[NPIX], cl[NPIX], whl[64];
  __shared__ float zbuf[4][64];
  int n = blockIdx.x, tid = threadIdx.x;
  if (tid < NPIX) {
    float s1 = 0.0f, s2 = 0.0f;
#pragma unroll
    for (int kc = 0; kc < 8; ++kc) {
      s1 += ws[WS_P1 + (kc * 64 + n) * 64 + tid];
      s2 += ws[WS_P2 + (kc * 64 + n) * 64 + tid];
    }
    gl[tid] = s1;
    cl[tid] = s1 + s2;
    whl[tid] = Wh[tid];
  }
  __syncthreads();
  int k = tid & 63, g = tid >> 6;
  float zp = 0.0f;
  if (k < NPIX) {
    int k2e = (g == 3) ? NPIX : (g * 13 + 13);
    const float* Mz = ws + WS_MF + n * 2401;
    for (int k2 = g * 13; k2 < k2e; ++k2) {
      float m = Mz[k2 * 49 + k];
      zp += tanh_f(tanh_f(m + gl[k2])) * whl[k2];
    }
  }
  zbuf[g][k] = zp;
  __syncthreads();
  if (tid < 64) {
    int lane = tid;
    float z = zbuf[0][lane] + zbuf[1][lane] + zbuf[2][lane] + zbuf[3][lane];
    float zm = (lane < NPIX) ? z : -1e30f;
    float m1 = zm;
    for (int off = 32; off; off >>= 1) m1 = fmaxf(m1, __shfl_xor(m1, off));
    float e = (lane < NPIX) ? __expf(z - m1) : 0.0f;
    float S1 = e;
    for (int off = 32; off; off >>= 1) S1 += __shfl_xor(S1, off);
    if (lane < NPIX) out[OUT_ALPHA + n * NPIX + lane] = e * rcp_fast(S1);
    float vz = (lane < NPIX) ? tanh_f(cl[lane]) * whl[lane] : 0.0f;
    for (int off = 32; off; off >>= 1) vz += __shfl_xor(vz, off);
    if (lane == 0) {
      float ze = vz;
      float m2 = fmaxf(m1, ze);
      float S2 = S1 * __expf(m1 - m2) + __expf(ze - m2);
      out[OUT_BETA + n] = __expf(ze - m2) * rcp_fast(S2);
    }
  }
}

// c_spatial^T[d][n] = sum_k alpha_t[n][k] * V[b][k][d]
__global__ __launch_bounds__(256) void k_cspatial(const float* __restrict__ V,
    const float* __restrict__ out, float* __restrict__ ws) {
  __shared__ float al[NPIX];
  int bid = blockIdx.x, tid = threadIdx.x;
  int n = bid & 63, b = n >> 3;
  int d = (bid >> 6) * 256 + tid;
  if (tid < NPIX) al[tid] = out[OUT_ALPHA + n * NPIX + tid];
  __syncthreads();
  float s = 0.0f;
#pragma unroll 7
  for (int k = 0; k < NPIX; ++k) s += al[k] * V[b * NPIX * CDIM + k * CDIM + d];
  ws[WS_CSPT + d * 64 + n] = s;
}

// spat GEMMs only (st 4..7) -> WS_GSPS slabs 32..63 ; grid (2,8,16)
__global__ __launch_bounds__(256) void k_gemm_spat(const float* __restrict__ Wspat,
    float* __restrict__ ws) {
  int c = blockIdx.x * 256 + threadIdx.x;
  int kc = blockIdx.y;
  int z = blockIdx.z;
  int st = 4 + (z >> 2), n0 = (z & 3) * 16;
  int q = st - 4;
  const float* A = ws + WS_CSPT + q * 32768;
  const float* W = Wspat + q * 262144;
  float* C = ws + WS_GSPS + (st * 8 + kc) * 32768;
  gemm16s(A, W, C, n0, kc * 64, 64, c);
}

// chat^T[c][n] = sigmoid(GA1)*SPAT + sigmoid(GA2)*(cchan@Wchan) + h
// reduces GSPS slabs (GA1 0..15, GA2 16..31, SPAT 32..63) and 16 cchan slabs
__global__ __launch_bounds__(256) void k_chat(const float* __restrict__ hid,
    const float* __restrict__ Wchan, float* __restrict__ ws) {
  __shared__ float cl[NPIX];
  int tid = threadIdx.x, n = blockIdx.y;
  int c = blockIdx.x * 256 + tid;
  if (tid < NPIX) {
    float s = 0.0f;
#pragma unroll
    for (int kc = 0; kc < 16; ++kc) s += ws[WS_CCH + (kc * 64 + n) * 52 + tid];
    cl[tid] = s;
  }
  __syncthreads();
  float acc = 0.0f;
#pragma unroll 7
  for (int k = 0; k < NPIX; ++k) acc += cl[k] * Wchan[k * H + c];
  int idx = n * H + c;
  float ga1 = 0.0f, ga2 = 0.0f, spat = 0.0f;
#pragma unroll
  for (int s = 0; s < 16; ++s)  ga1 += ws[WS_GSPS + s * 32768 + idx];
#pragma unroll
  for (int s = 16; s < 32; ++s) ga2 += ws[WS_GSPS + s * 32768 + idx];
#pragma unroll
  for (int s = 32; s < 64; ++s) spat += ws[WS_GSPS + s * 32768 + idx];
  float chat = sigmoid_f(ga1) * spat + sigmoid_f(ga2) * acc + hid[idx];
  ws[WS_CHT + c * 64 + n] = chat;
}

// scores partial slabs: grid (20, 4, 4); thread = 2 cols x 16 tokens
__global__ __launch_bounds__(256) void k_gemm_scores(const float* __restrict__ Wmlp,
    float* __restrict__ ws) {
  int tid = threadIdx.x;
  int c0 = blockIdx.x * 512 + tid * 2;
  if (c0 >= VOCAB) return;
  int kc = blockIdx.y, k0 = kc * 128;
  int n0 = blockIdx.z * 16;
  const float* A = ws + WS_CHT;
  const float2* W2 = (const float2*)Wmlp;
  int cw = c0 >> 1;
  float2 acc[16];
#pragma unroll
  for (int j = 0; j < 16; ++j) acc[j] = make_float2(0.f, 0.f);
#pragma unroll 4
  for (int kk = 0; kk < 128; ++kk) {
    int k = k0 + kk;
    float2 w = W2[k * (VOCAB / 2) + cw];
    const float4* A4 = (const float4*)(A + k * 64 + n0);
#pragma unroll
    for (int q = 0; q < 4; ++q) {
      float4 a = A4[q];
      acc[q * 4 + 0].x += a.x * w.x; acc[q * 4 + 0].y += a.x * w.y;
      acc[q * 4 + 1].x += a.y * w.x; acc[q * 4 + 1].y += a.y * w.y;
      acc[q * 4 + 2].x += a.z * w.x; acc[q * 4 + 2].y += a.z * w.y;
      acc[q * 4 + 3].x += a.w * w.x; acc[q * 4 + 3].y += a.w * w.y;
    }
  }
  float* slab = ws + WS_SCS + kc * 640000;
#pragma unroll
  for (int j = 0; j < 16; ++j)
    ((float2*)(slab + (n0 + j) * VOCAB))[cw] = acc[j];
}

// out[n][c] = bmlp[c] + sum of 4 score slabs ; grid (40, 64)
__global__ __launch_bounds__(256) void k_red_scores(const float* __restrict__ bmlp,
    float* __restrict__ ws, float* __restrict__ out) {
  int c = blockIdx.x * 256 + threadIdx.x, n = blockIdx.y;
  if (c >= VOCAB) return;
  int idx = n * VOCAB + c;
  float v = bmlp[c];
#pragma unroll
  for (int s = 0; s < 4; ++s) v += ws[WS_SCS + s * 640000 + idx];
  out[idx] = v;
}

extern "C" void kernel_launch(void* const* d_in, const int* in_sizes, int n_in,
                              void* d_out, int out_size, void* d_ws, size_t ws_size,
                              hipStream_t stream) {
  const float* x     = (const float*)d_in[0];
  const float* hid   = (const float*)d_in[1];
  const float* cells = (const float*)d_in[2];
  const float* V     = (const float*)d_in[3];
  const float* Wsx   = (const float*)d_in[4];
  const float* Wsh   = (const float*)d_in[5];
  const float* Wv    = (const float*)d_in[6];
  const float* Wg    = (const float*)d_in[7];
  const float* Ws_   = (const float*)d_in[8];
  const float* Wh    = (const float*)d_in[9];
  const float* Wfeat = (const float*)d_in[10];
  const float* Wcxt  = (const float*)d_in[11];
  const float* Wg2   = (const float*)d_in[12];
  const float* Wspat = (const float*)d_in[13];
  const float* Wchan = (const float*)d_in[14];
  const float* Wgvs  = (const float*)d_in[15];
  const float* Wgvc  = (const float*)d_in[16];
  const float* Wghs  = (const float*)d_in[17];
  const float* Wghc  = (const float*)d_in[18];
  const float* Wmlp  = (const float*)d_in[19];
  const float* bmlp  = (const float*)d_in[20];
  float* ws  = (float*)d_ws;
  float* out = (float*)d_out;

  hipLaunchKernelGGL(k_prep, dim3(448), dim3(256), 0, stream, x, hid, V, ws);
  hipLaunchKernelGGL(k_gemm_sg2, dim3(2, 16, 12), dim3(256), 0, stream, Wsx, Wsh, Wg2, ws);
  hipLaunchKernelGGL(k_act_s, dim3(128), dim3(256), 0, stream, cells, ws);
  hipLaunchKernelGGL(k_cxt_gates, dim3(768), dim3(256), 0, stream, Wfeat, Wcxt, Wgvs, Wghs, Wgvc, Wghc, ws);
  hipLaunchKernelGGL(k_softmax_cshwg, dim3(192), dim3(256), 0, stream, hid, Wg, Ws_, ws);
  hipLaunchKernelGGL(k_attnM, dim3(1024), dim3(256), 0, stream, V, Wv, ws);
  hipLaunchKernelGGL(k_redM, dim3(10, 64), dim3(256), 0, stream, ws);
  hipLaunchKernelGGL(k_zt, dim3(64), dim3(256), 0, stream, Wh, ws, out);
  hipLaunchKernelGGL(k_cspatial, dim3(512), dim3(256), 0, stream, V, out, ws);
  hipLaunchKernelGGL(k_gemm_spat, dim3(2, 8, 16), dim3(256), 0, stream, Wspat, ws);
  hipLaunchKernelGGL(k_chat, dim3(2, 64), dim3(256), 0, stream, hid, Wchan, ws);
  hipLaunchKernelGGL(k_gemm_scores, dim3(20, 4, 4), dim3(256), 0, stream, Wmlp, ws);
  hipLaunchKernelGGL(k_red_scores, dim3(40, 64), dim3(256), 0, stream, bmlp, ws, out);
}

// Round 10
// 236.303 us; speedup vs baseline: 1.1513x; 1.0748x over previous
//
#include <hip/hip_runtime.h>

#define H 512
#define NTOK 64
#define NPIX 49
#define CDIM 2048
#define VOCAB 10000

// ws layout (float offsets). NO region requires zero-init (all plain-stored).
#define WS_S      0         // 64x512
#define WS_ST     32768     // 512x64
#define WS_HT     65536     // 512x64
#define WS_XT     98304     // 512x64
#define WS_HPT    131072    // 512x64
#define WS_FM     163840    // 8x2048
#define WS_G2F    180224    // 64x512 reduced G2
#define WS_P1     212992    // 8 kc x 64 n x 64  (h@Wg partials)
#define WS_P2     245760    // 8 kc x 64 n x 64  (s@Ws partials)
#define WS_CCH    278528    // 16 kc x 64 n x 52 (cchan partials)
#define WS_A0     331776    // 64x2048 RAW cxt; CSPT / CHT alias after death
#define WS_CSPT   331776
#define WS_CHT    331776
// disjoint slab regions (ws is ~268MB; no time-sharing needed)
#define WS_SG2S   462848    // 48 x 32768  sg2 slabs (st*16+kc)
#define WS_GSPS   2035712   // 64 x 32768  gates+spat slabs (st*8+kc)
#define WS_MS     4132864   // 16 x 153664 M partial slabs
#define WS_SCS    6591488   // 4 x 640000  score slabs
#define WS_MF     9151488   // 64 x 2401 reduced M
// end = 9305152 floats ~= 37.2 MB

#define OUT_ALPHA 640000
#define OUT_BETA  643136

typedef __attribute__((ext_vector_type(8))) short short8;
typedef __attribute__((ext_vector_type(4))) float floatx4;

__device__ __forceinline__ float rcp_fast(float x) {
#if __has_builtin(__builtin_amdgcn_rcpf)
  return __builtin_amdgcn_rcpf(x);
#else
  return 1.0f / x;
#endif
}
__device__ __forceinline__ float tanh_f(float x) {
  float e = __expf(2.0f * x);
  return 1.0f - 2.0f * rcp_fast(e + 1.0f);
}
__device__ __forceinline__ float sigmoid_f(float x) {
  return rcp_fast(1.0f + __expf(-x));
}
__device__ __forceinline__ short f2bf(float x) {  // RNE fp32->bf16
  union { float f; unsigned u; } un; un.f = x;
  unsigned r = un.u + 0x7FFFu + ((un.u >> 16) & 1u);
  return (short)(r >> 16);
}
__device__ __forceinline__ float bf2f(unsigned short h) {
  union { unsigned u; float f; } cv; cv.u = ((unsigned)h) << 16;
  return cv.f;
}

// prep: featmean (64 blocks) + transposes x/h/hprev (384 blocks)
__global__ __launch_bounds__(256) void k_prep(const float* __restrict__ x,
    const float* __restrict__ hid, const float* __restrict__ V,
    float* __restrict__ ws) {
  int bid = blockIdx.x, tid = threadIdx.x;
  if (bid < 64) {
    int b = bid >> 3, c = (bid & 7) * 256 + tid;
    float s = 0.0f;
    for (int k = 0; k < NPIX; ++k) s += V[b * NPIX * CDIM + k * CDIM + c];
    ws[WS_FM + b * CDIM + c] = s * (1.0f / NPIX);
  } else {
    int i3 = (bid - 64) * 256 + tid;
    int role = i3 >> 15, idx = i3 & 32767;
    int n = idx >> 9, k = idx & 511;
    if (role == 0)      ws[WS_XT + k * 64 + n] = x[idx];
    else if (role == 1) ws[WS_HT + k * 64 + n] = hid[idx];
    else                ws[WS_HPT + k * 64 + n] = (n & 7) ? hid[idx - 512] : 0.0f;
  }
}

// partial-slab gemm: Cslab[(n0+j)*512+c] = sum_{k0..k0+nk} A^T[k][n0+j] * W[k*512+c]
__device__ __forceinline__ void gemm16s(const float* __restrict__ A,
    const float* __restrict__ W, float* __restrict__ Cslab,
    int n0, int k0, int nk, int c) {
  float acc[16];
#pragma unroll
  for (int j = 0; j < 16; ++j) acc[j] = 0.0f;
#pragma unroll 4
  for (int kk = 0; kk < nk; ++kk) {
    int k = k0 + kk;
    float w = W[k * 512 + c];
    const float4* A4 = (const float4*)(A + k * 64 + n0);
#pragma unroll
    for (int q = 0; q < 4; ++q) {
      float4 a = A4[q];
      acc[q * 4 + 0] += a.x * w;
      acc[q * 4 + 1] += a.y * w;
      acc[q * 4 + 2] += a.z * w;
      acc[q * 4 + 3] += a.w * w;
    }
  }
#pragma unroll
  for (int j = 0; j < 16; ++j) Cslab[(n0 + j) * 512 + c] = acc[j];
}

// streams 0:(XT,Wsx) 1:(HPT,Wsh) 2:(HT,Wg2) -> slabs st*16+kc ; grid (2,16,12)
__global__ __launch_bounds__(256) void k_gemm_sg2(const float* __restrict__ Wsx,
    const float* __restrict__ Wsh, const float* __restrict__ Wg2,
    float* __restrict__ ws) {
  int c = blockIdx.x * 256 + threadIdx.x;
  int kc = blockIdx.y;
  int z = blockIdx.z, st = z >> 2, n0 = (z & 3) * 16;
  const float* A = (st == 0) ? ws + WS_XT : (st == 1) ? ws + WS_HPT : ws + WS_HT;
  const float* W = (st == 0) ? Wsx : (st == 1) ? Wsh : Wg2;
  float* C = ws + WS_SG2S + (st * 16 + kc) * 32768;
  gemm16s(A, W, C, n0, kc * 32, 32, c);
}

// reduce slabs: S = sigmoid(sum slabs 0..31)*tanh(cells) -> S,ST ; G2F = sum slabs 32..47
__global__ __launch_bounds__(256) void k_act_s(const float* __restrict__ cells,
    float* __restrict__ ws) {
  int idx = blockIdx.x * 256 + threadIdx.x;
  int n = idx >> 9, c = idx & 511;
  float sa = 0.0f, g = 0.0f;
#pragma unroll
  for (int s = 0; s < 32; ++s) sa += ws[WS_SG2S + s * 32768 + idx];
#pragma unroll
  for (int s = 32; s < 48; ++s) g += ws[WS_SG2S + s * 32768 + idx];
  float v = sigmoid_f(sa) * tanh_f(cells[idx]);
  ws[WS_S + idx] = v;
  ws[WS_ST + c * 64 + n] = v;
  ws[WS_G2F + idx] = g;
}

// bid<512: cxt[n][c] (raw, no softmax) ; 512<=bid<768: gates GEMMs ; bid>=768: cs_hwg
__global__ __launch_bounds__(256) void k_mid(const float* __restrict__ Wfeat,
    const float* __restrict__ Wcxt, const float* __restrict__ Wgvs,
    const float* __restrict__ Wghs, const float* __restrict__ Wgvc,
    const float* __restrict__ Wghc, const float* __restrict__ hid,
    const float* __restrict__ Wg, const float* __restrict__ Ws_,
    float* __restrict__ ws) {
  int bid = blockIdx.x, tid = threadIdx.x;
  if (bid < 512) {
    __shared__ float2 fw[512];
    __shared__ float g2l[512];
    int n = bid & 63, b = n >> 3;
    int c = (bid >> 6) * 256 + tid;
    for (int i = tid; i < 512; i += 256) {
      fw[i] = make_float2(Wfeat[i], Wcxt[i]);
      g2l[i] = ws[WS_G2F + n * H + i];
    }
    __syncthreads();
    float fm = ws[WS_FM + b * CDIM + c];
    float acc = 0.0f;
#pragma unroll 4
    for (int j = 0; j < 512; ++j) {
      float2 p = fw[j];
      acc += tanh_f(fm * p.x + g2l[j]) * p.y;
    }
    ws[WS_A0 + n * CDIM + c] = acc;
  } else if (bid < 768) {
    int gi = bid - 512;                 // 0..255
    int c = (gi & 1) * 256 + tid;
    int rest = gi >> 1;                 // 0..127
    int kc = rest & 7;
    int zz = rest >> 3;                 // 0..15
    int st = zz >> 2, n0 = (zz & 3) * 16;
    const float* A = ws + ((st & 1) ? WS_HT : WS_ST);
    const float* W = (st == 0) ? Wgvs : (st == 1) ? Wghs : (st == 2) ? Wgvc : Wghc;
    float* C = ws + WS_GSPS + (st * 8 + kc) * 32768;
    gemm16s(A, W, C, n0, kc * 64, 64, c);
  } else {
    int bidx = bid - 768;               // 0..127
    int n = bidx & 63, half = bidx >> 6;
    int k2 = tid & 63, w = tid >> 6;
    int kc = half * 4 + w;
    const float* hrow = hid + n * H;
    const float* srow = ws + WS_S + n * H;
    float a1 = 0.0f, a2 = 0.0f;
#pragma unroll 4
    for (int kk = 0; kk < 64; ++kk) {
      int k = kc * 64 + kk;
      if (k2 < NPIX) {
        a1 += hrow[k] * Wg[k * NPIX + k2];
        a2 += srow[k] * Ws_[k * NPIX + k2];
      }
    }
    if (k2 < NPIX) {
      ws[WS_P1 + (kc * 64 + n) * 64 + k2] = a1;
      ws[WS_P2 + (kc * 64 + n) * 64 + k2] = a2;
    }
  }
}

// attnM via bf16 MFMA, softmax fused. grid 1024 = (16 kc)x(64 n).
// Block reads raw cxt row -> (m, inv); alpha0 applied on the fly during A staging.
__global__ __launch_bounds__(256) void k_attnM(const float* __restrict__ V,
    const float* __restrict__ Wv, float* __restrict__ ws) {
  __shared__ __align__(16) short al[64 * 136];
  __shared__ __align__(16) short bl[64 * 136];
  __shared__ float red[8];
  int tid = threadIdx.x, bid = blockIdx.x;
  int kc = bid >> 6, n = bid & 63, b = n >> 3;
  int c0 = kc * 128;
  const float* cr = ws + WS_A0 + n * CDIM;
  const float* Vb = V + b * NPIX * CDIM + c0;
  int lane = tid & 63, w = tid >> 6;
  // softmax stats over the full 2048 row
  float v[8];
  float vmax = -1e30f;
#pragma unroll
  for (int i = 0; i < 8; ++i) { v[i] = cr[tid + i * 256]; vmax = fmaxf(vmax, v[i]); }
  for (int off = 32; off; off >>= 1) vmax = fmaxf(vmax, __shfl_xor(vmax, off));
  if (lane == 0) red[w] = vmax;
  __syncthreads();
  float m = fmaxf(fmaxf(red[0], red[1]), fmaxf(red[2], red[3]));
  float ss = 0.0f;
#pragma unroll
  for (int i = 0; i < 8; ++i) ss += __expf(v[i] - m);
  for (int off = 32; off; off >>= 1) ss += __shfl_xor(ss, off);
  if (lane == 0) red[4 + w] = ss;
  __syncthreads();
  float inv = rcp_fast(red[4] + red[5] + red[6] + red[7]);
  // staging (alpha0 on the fly)
  {
    int cc = tid & 127;
    float a0c = __expf(cr[c0 + cc] - m) * inv;
    for (int k = tid >> 7; k < NPIX; k += 2)
      al[k * 136 + cc] = f2bf(a0c * Vb[k * CDIM + cc]);
  }
  for (int idx = tid; idx < 128 * 64; idx += 256) {
    int cc = idx >> 6, r = idx & 63;
    if (r < NPIX) bl[r * 136 + cc] = f2bf(Wv[(c0 + cc) * NPIX + r]);
  }
  __syncthreads();
  // cchan partial (sum over cc of A row)
  if (tid < NPIX) {
    float cch = 0.0f;
    const unsigned short* ar = (const unsigned short*)(al + tid * 136);
#pragma unroll 8
    for (int cc = 0; cc < 128; ++cc) cch += bf2f(ar[cc]);
    ws[WS_CCH + (kc * 64 + n) * 52 + tid] = cch * (1.0f / CDIM);
  }
  int qm = lane >> 4, mr = lane & 15;
  floatx4 acc[4];
#pragma unroll
  for (int i = 0; i < 4; ++i) acc[i] = (floatx4){0.f, 0.f, 0.f, 0.f};
#pragma unroll
  for (int ks = 0; ks < 4; ++ks) {
    int cb = ks * 32 + qm * 8;
    short8 bf = *(const short8*)&bl[(w * 16 + mr) * 136 + cb];
#pragma unroll
    for (int i = 0; i < 4; ++i) {
      short8 af = *(const short8*)&al[(i * 16 + mr) * 136 + cb];
      acc[i] = __builtin_amdgcn_mfma_f32_16x16x32_bf16(af, bf, acc[i], 0, 0, 0);
    }
  }
  __syncthreads();           // all MFMA LDS reads done; reuse al as fp32 out tile
  float* ml = (float*)al;    // 2401 floats fits in al
  int k2 = w * 16 + mr;
  if (k2 < NPIX) {
#pragma unroll
    for (int i = 0; i < 4; ++i) {
#pragma unroll
      for (int r = 0; r < 4; ++r) {
        int kp = i * 16 + qm * 4 + r;
        if (kp < NPIX) ml[k2 * 49 + kp] = acc[i][r];
      }
    }
  }
  __syncthreads();
  float* Mp = ws + WS_MS + kc * 153664 + n * 2401;
  for (int idx = tid; idx < 2401; idx += 256) Mp[idx] = ml[idx];
}

// reduce the 16 M slabs -> MF[n][2401] ; grid (10, 64)
__global__ __launch_bounds__(256) void k_redM(float* __restrict__ ws) {
  int n = blockIdx.y;
  int i = blockIdx.x * 256 + threadIdx.x;
  if (i < 2401) {
    float m = 0.0f;
#pragma unroll
    for (int s = 0; s < 16; ++s) m += ws[WS_MS + s * 153664 + n * 2401 + i];
    ws[WS_MF + n * 2401 + i] = m;
  }
}

// zt: reduce P1/P2; z from single MF slab; alpha, beta
__global__ __launch_bounds__(256) void k_zt(const float* __restrict__ Wh,
    float* __restrict__ ws, float* __restrict__ out) {
  __shared__ float gl[NPIX], cl[NPIX], whl[64];
  __shared__ float zbuf[4][64];
  int n = blockIdx.x, tid = threadIdx.x;
  if (tid < NPIX) {
    float s1 = 0.0f, s2 = 0.0f;
#pragma unroll
    for (int kc = 0; kc < 8; ++kc) {
      s1 += ws[WS_P1 + (kc * 64 + n) * 64 + tid];
      s2 += ws[WS_P2 + (kc * 64 + n) * 64 + tid];
    }
    gl[tid] = s1;
    cl[tid] = s1 + s2;
    whl[tid] = Wh[tid];
  }
  __syncthreads();
  int k = tid & 63, g = tid >> 6;
  float zp = 0.0f;
  if (k < NPIX) {
    int k2e = (g == 3) ? NPIX : (g * 13 + 13);
    const float* Mz = ws + WS_MF + n * 2401;
    for (int k2 = g * 13; k2 < k2e; ++k2) {
      float m = Mz[k2 * 49 + k];
      zp += tanh_f(tanh_f(m + gl[k2])) * whl[k2];
    }
  }
  zbuf[g][k] = zp;
  __syncthreads();
  if (tid < 64) {
    int lane = tid;
    float z = zbuf[0][lane] + zbuf[1][lane] + zbuf[2][lane] + zbuf[3][lane];
    float zm = (lane < NPIX) ? z : -1e30f;
    float m1 = zm;
    for (int off = 32; off; off >>= 1) m1 = fmaxf(m1, __shfl_xor(m1, off));
    float e = (lane < NPIX) ? __expf(z - m1) : 0.0f;
    float S1 = e;
    for (int off = 32; off; off >>= 1) S1 += __shfl_xor(S1, off);
    if (lane < NPIX) out[OUT_ALPHA + n * NPIX + lane] = e * rcp_fast(S1);
    float vz = (lane < NPIX) ? tanh_f(cl[lane]) * whl[lane] : 0.0f;
    for (int off = 32; off; off >>= 1) vz += __shfl_xor(vz, off);
    if (lane == 0) {
      float ze = vz;
      float m2 = fmaxf(m1, ze);
      float S2 = S1 * __expf(m1 - m2) + __expf(ze - m2);
      out[OUT_BETA + n] = __expf(ze - m2) * rcp_fast(S2);
    }
  }
}

// c_spatial^T[d][n] = sum_k alpha_t[n][k] * V[b][k][d]
__global__ __launch_bounds__(256) void k_cspatial(const float* __restrict__ V,
    const float* __restrict__ out, float* __restrict__ ws) {
  __shared__ float al[NPIX];
  int bid = blockIdx.x, tid = threadIdx.x;
  int n = bid & 63, b = n >> 3;
  int d = (bid >> 6) * 256 + tid;
  if (tid < NPIX) al[tid] = out[OUT_ALPHA + n * NPIX + tid];
  __syncthreads();
  float s = 0.0f;
#pragma unroll 7
  for (int k = 0; k < NPIX; ++k) s += al[k] * V[b * NPIX * CDIM + k * CDIM + d];
  ws[WS_CSPT + d * 64 + n] = s;
}

// spat GEMMs (st 4..7) -> WS_GSPS slabs 32..63 ; grid (2,8,16)
__global__ __launch_bounds__(256) void k_gemm_spat(const float* __restrict__ Wspat,
    float* __restrict__ ws) {
  int c = blockIdx.x * 256 + threadIdx.x;
  int kc = blockIdx.y;
  int z = blockIdx.z;
  int st = 4 + (z >> 2), n0 = (z & 3) * 16;
  int q = st - 4;
  const float* A = ws + WS_CSPT + q * 32768;
  const float* W = Wspat + q * 262144;
  float* C = ws + WS_GSPS + (st * 8 + kc) * 32768;
  gemm16s(A, W, C, n0, kc * 64, 64, c);
}

// chat^T[c][n] = sigmoid(GA1)*SPAT + sigmoid(GA2)*(cchan@Wchan) + h
__global__ __launch_bounds__(256) void k_chat(const float* __restrict__ hid,
    const float* __restrict__ Wchan, float* __restrict__ ws) {
  __shared__ float cl[NPIX];
  int tid = threadIdx.x, n = blockIdx.y;
  int c = blockIdx.x * 256 + tid;
  if (tid < NPIX) {
    float s = 0.0f;
#pragma unroll
    for (int kc = 0; kc < 16; ++kc) s += ws[WS_CCH + (kc * 64 + n) * 52 + tid];
    cl[tid] = s;
  }
  __syncthreads();
  float acc = 0.0f;
#pragma unroll 7
  for (int k = 0; k < NPIX; ++k) acc += cl[k] * Wchan[k * H + c];
  int idx = n * H + c;
  float ga1 = 0.0f, ga2 = 0.0f, spat = 0.0f;
#pragma unroll
  for (int s = 0; s < 16; ++s)  ga1 += ws[WS_GSPS + s * 32768 + idx];
#pragma unroll
  for (int s = 16; s < 32; ++s) ga2 += ws[WS_GSPS + s * 32768 + idx];
#pragma unroll
  for (int s = 32; s < 64; ++s) spat += ws[WS_GSPS + s * 32768 + idx];
  float chat = sigmoid_f(ga1) * spat + sigmoid_f(ga2) * acc + hid[idx];
  ws[WS_CHT + c * 64 + n] = chat;
}

// scores partial slabs: grid (20, 4, 4); thread = 2 cols x 16 tokens
__global__ __launch_bounds__(256) void k_gemm_scores(const float* __restrict__ Wmlp,
    float* __restrict__ ws) {
  int tid = threadIdx.x;
  int c0 = blockIdx.x * 512 + tid * 2;
  if (c0 >= VOCAB) return;
  int kc = blockIdx.y, k0 = kc * 128;
  int n0 = blockIdx.z * 16;
  const float* A = ws + WS_CHT;
  const float2* W2 = (const float2*)Wmlp;
  int cw = c0 >> 1;
  float2 acc[16];
#pragma unroll
  for (int j = 0; j < 16; ++j) acc[j] = make_float2(0.f, 0.f);
#pragma unroll 4
  for (int kk = 0; kk < 128; ++kk) {
    int k = k0 + kk;
    float2 w = W2[k * (VOCAB / 2) + cw];
    const float4* A4 = (const float4*)(A + k * 64 + n0);
#pragma unroll
    for (int q = 0; q < 4; ++q) {
      float4 a = A4[q];
      acc[q * 4 + 0].x += a.x * w.x; acc[q * 4 + 0].y += a.x * w.y;
      acc[q * 4 + 1].x += a.y * w.x; acc[q * 4 + 1].y += a.y * w.y;
      acc[q * 4 + 2].x += a.z * w.x; acc[q * 4 + 2].y += a.z * w.y;
      acc[q * 4 + 3].x += a.w * w.x; acc[q * 4 + 3].y += a.w * w.y;
    }
  }
  float* slab = ws + WS_SCS + kc * 640000;
#pragma unroll
  for (int j = 0; j < 16; ++j)
    ((float2*)(slab + (n0 + j) * VOCAB))[cw] = acc[j];
}

// out[n][c] = bmlp[c] + sum of 4 score slabs ; float4 ; grid (10, 64)
__global__ __launch_bounds__(256) void k_red_scores(const float* __restrict__ bmlp,
    float* __restrict__ ws, float* __restrict__ out) {
  int c4 = blockIdx.x * 256 + threadIdx.x, n = blockIdx.y;
  if (c4 >= VOCAB / 4) return;
  const float4* b4 = (const float4*)bmlp;
  float4 v = b4[c4];
#pragma unroll
  for (int s = 0; s < 4; ++s) {
    float4 p = ((const float4*)(ws + WS_SCS + s * 640000 + n * VOCAB))[c4];
    v.x += p.x; v.y += p.y; v.z += p.z; v.w += p.w;
  }
  ((float4*)(out + n * VOCAB))[c4] = v;
}

extern "C" void kernel_launch(void* const* d_in, const int* in_sizes, int n_in,
                              void* d_out, int out_size, void* d_ws, size_t ws_size,
                              hipStream_t stream) {
  const float* x     = (const float*)d_in[0];
  const float* hid   = (const float*)d_in[1];
  const float* cells = (const float*)d_in[2];
  const float* V     = (const float*)d_in[3];
  const float* Wsx   = (const float*)d_in[4];
  const float* Wsh   = (const float*)d_in[5];
  const float* Wv    = (const float*)d_in[6];
  const float* Wg    = (const float*)d_in[7];
  const float* Ws_   = (const float*)d_in[8];
  const float* Wh    = (const float*)d_in[9];
  const float* Wfeat = (const float*)d_in[10];
  const float* Wcxt  = (const float*)d_in[11];
  const float* Wg2   = (const float*)d_in[12];
  const float* Wspat = (const float*)d_in[13];
  const float* Wchan = (const float*)d_in[14];
  const float* Wgvs  = (const float*)d_in[15];
  const float* Wgvc  = (const float*)d_in[16];
  const float* Wghs  = (const float*)d_in[17];
  const float* Wghc  = (const float*)d_in[18];
  const float* Wmlp  = (const float*)d_in[19];
  const float* bmlp  = (const float*)d_in[20];
  float* ws  = (float*)d_ws;
  float* out = (float*)d_out;

  hipLaunchKernelGGL(k_prep, dim3(448), dim3(256), 0, stream, x, hid, V, ws);
  hipLaunchKernelGGL(k_gemm_sg2, dim3(2, 16, 12), dim3(256), 0, stream, Wsx, Wsh, Wg2, ws);
  hipLaunchKernelGGL(k_act_s, dim3(128), dim3(256), 0, stream, cells, ws);
  hipLaunchKernelGGL(k_mid, dim3(896), dim3(256), 0, stream, Wfeat, Wcxt, Wgvs, Wghs, Wgvc, Wghc, hid, Wg, Ws_, ws);
  hipLaunchKernelGGL(k_attnM, dim3(1024), dim3(256), 0, stream, V, Wv, ws);
  hipLaunchKernelGGL(k_redM, dim3(10, 64), dim3(256), 0, stream, ws);
  hipLaunchKernelGGL(k_zt, dim3(64), dim3(256), 0, stream, Wh, ws, out);
  hipLaunchKernelGGL(k_cspatial, dim3(512), dim3(256), 0, stream, V, out, ws);
  hipLaunchKernelGGL(k_gemm_spat, dim3(2, 8, 16), dim3(256), 0, stream, Wspat, ws);
  hipLaunchKernelGGL(k_chat, dim3(2, 64), dim3(256), 0, stream, hid, Wchan, ws);
  hipLaunchKernelGGL(k_gemm_scores, dim3(20, 4, 4), dim3(256), 0, stream, Wmlp, ws);
  hipLaunchKernelGGL(k_red_scores, dim3(10, 64), dim3(256), 0, stream, bmlp, ws, out);
}

// Round 11
// 221.225 us; speedup vs baseline: 1.2298x; 1.0682x over previous
//
#include <hip/hip_runtime.h>

#define H 512
#define NTOK 64
#define NPIX 49
#define CDIM 2048
#define VOCAB 10000

// ws layout (float offsets). NO region requires zero-init (all plain-stored).
#define WS_S      0         // 64x512
#define WS_FM     163840    // 8x2048
#define WS_G2F    180224    // 64x512 reduced G2
#define WS_P1     212992    // 8 kc x 64 n x 64  (h@Wg partials)
#define WS_P2     245760    // 8 kc x 64 n x 64  (s@Ws partials)
#define WS_CCH    278528    // 16 kc x 64 n x 52 (cchan partials)
#define WS_A0     331776    // 64x2048 RAW cxt; CSPT alias; CHB bf16 alias after death
#define WS_CSPT   331776
#define WS_CHT    331776    // chat bf16 [n][512] (shorts)
// disjoint slab regions (ws is ~268MB; no time-sharing needed)
#define WS_SG2S   462848    // 48 x 32768  sg2 slabs (st*16+kc)
#define WS_GSPS   2035712   // 64 x 32768  gates+spat slabs (st*8+kc)
#define WS_MS     4132864   // 16 x 153664 M partial slabs
#define WS_SCS    6591488   // 4 x 640000  score slabs
#define WS_MF     9151488   // 64 x 2401 reduced M
// end = 9305152 floats ~= 37.2 MB

#define OUT_ALPHA 640000
#define OUT_BETA  643136

typedef __attribute__((ext_vector_type(8))) short short8;
typedef __attribute__((ext_vector_type(4))) float floatx4;

__device__ __forceinline__ float rcp_fast(float x) {
#if __has_builtin(__builtin_amdgcn_rcpf)
  return __builtin_amdgcn_rcpf(x);
#else
  return 1.0f / x;
#endif
}
__device__ __forceinline__ float tanh_f(float x) {
  float e = __expf(2.0f * x);
  return 1.0f - 2.0f * rcp_fast(e + 1.0f);
}
__device__ __forceinline__ float sigmoid_f(float x) {
  return rcp_fast(1.0f + __expf(-x));
}
__device__ __forceinline__ short f2bf(float x) {  // RNE fp32->bf16
  union { float f; unsigned u; } un; un.f = x;
  unsigned r = un.u + 0x7FFFu + ((un.u >> 16) & 1u);
  return (short)(r >> 16);
}
__device__ __forceinline__ float bf2f(unsigned short h) {
  union { unsigned u; float f; } cv; cv.u = ((unsigned)h) << 16;
  return cv.f;
}

// sg2 + featmean. bid<384: gemm streams 0:(x,Wsx) 1:(hprev,Wsh) 2:(h,Wg2)
// with self-staged A chunk; bid>=384: featmean.
__global__ __launch_bounds__(256) void k_sg2(const float* __restrict__ Wsx,
    const float* __restrict__ Wsh, const float* __restrict__ Wg2,
    const float* __restrict__ x, const float* __restrict__ hid,
    const float* __restrict__ V, float* __restrict__ ws) {
  int bid = blockIdx.x, tid = threadIdx.x;
  if (bid < 384) {
    __shared__ float aT[32 * 20];
    int c2 = bid & 1, kc = (bid >> 1) & 15, z = bid >> 5;   // z 0..11
    int st = z >> 2, n0 = (z & 3) * 16;
    int c = c2 * 256 + tid;
    int k0 = kc * 32;
    const float* W = (st == 0) ? Wsx : (st == 1) ? Wsh : Wg2;
    for (int i = tid; i < 512; i += 256) {
      int nn = i >> 5, kk = i & 31;
      int tok = n0 + nn;
      float v;
      if (st == 0)      v = x[tok * 512 + k0 + kk];
      else if (st == 1) v = (tok & 7) ? hid[(tok - 1) * 512 + k0 + kk] : 0.0f;
      else              v = hid[tok * 512 + k0 + kk];
      aT[kk * 20 + nn] = v;
    }
    __syncthreads();
    float acc[16];
#pragma unroll
    for (int j = 0; j < 16; ++j) acc[j] = 0.0f;
#pragma unroll 4
    for (int kk = 0; kk < 32; ++kk) {
      float w = W[(k0 + kk) * 512 + c];
      const float4* a4 = (const float4*)&aT[kk * 20];
#pragma unroll
      for (int q = 0; q < 4; ++q) {
        float4 a = a4[q];
        acc[q * 4 + 0] += a.x * w;
        acc[q * 4 + 1] += a.y * w;
        acc[q * 4 + 2] += a.z * w;
        acc[q * 4 + 3] += a.w * w;
      }
    }
    float* C = ws + WS_SG2S + (st * 16 + kc) * 32768;
#pragma unroll
    for (int j = 0; j < 16; ++j) C[(n0 + j) * 512 + c] = acc[j];
  } else {
    int fb = bid - 384;
    int b = fb >> 3, c = (fb & 7) * 256 + tid;
    float s = 0.0f;
    for (int k = 0; k < NPIX; ++k) s += V[b * NPIX * CDIM + k * CDIM + c];
    ws[WS_FM + b * CDIM + c] = s * (1.0f / NPIX);
  }
}

// reduce slabs: S = sigmoid(sum slabs 0..31)*tanh(cells) -> S ; G2F = sum slabs 32..47
__global__ __launch_bounds__(256) void k_act_s(const float* __restrict__ cells,
    float* __restrict__ ws) {
  int idx = blockIdx.x * 256 + threadIdx.x;
  float sa = 0.0f, g = 0.0f;
#pragma unroll
  for (int s = 0; s < 32; ++s) sa += ws[WS_SG2S + s * 32768 + idx];
#pragma unroll
  for (int s = 32; s < 48; ++s) g += ws[WS_SG2S + s * 32768 + idx];
  ws[WS_S + idx] = sigmoid_f(sa) * tanh_f(cells[idx]);
  ws[WS_G2F + idx] = g;
}

// bid<512: cxt raw ; 512<=bid<768: gates GEMMs (self-staged) ; bid>=768: cs_hwg
__global__ __launch_bounds__(256) void k_mid(const float* __restrict__ Wfeat,
    const float* __restrict__ Wcxt, const float* __restrict__ Wgvs,
    const float* __restrict__ Wghs, const float* __restrict__ Wgvc,
    const float* __restrict__ Wghc, const float* __restrict__ hid,
    const float* __restrict__ Wg, const float* __restrict__ Ws_,
    float* __restrict__ ws) {
  int bid = blockIdx.x, tid = threadIdx.x;
  if (bid < 512) {
    __shared__ float2 fw[512];
    __shared__ float g2l[512];
    int n = bid & 63, b = n >> 3;
    int c = (bid >> 6) * 256 + tid;
    for (int i = tid; i < 512; i += 256) {
      fw[i] = make_float2(Wfeat[i], Wcxt[i]);
      g2l[i] = ws[WS_G2F + n * H + i];
    }
    __syncthreads();
    float fm = ws[WS_FM + b * CDIM + c];
    float acc = 0.0f;
#pragma unroll 4
    for (int j = 0; j < 512; ++j) {
      float2 p = fw[j];
      acc += tanh_f(fm * p.x + g2l[j]) * p.y;
    }
    ws[WS_A0 + n * CDIM + c] = acc;
  } else if (bid < 768) {
    __shared__ float aT[64 * 20];
    int gi = bid - 512;                 // 0..255
    int c = (gi & 1) * 256 + tid;
    int rest = gi >> 1;                 // 0..127
    int kc = rest & 7;
    int zz = rest >> 3;                 // 0..15
    int st = zz >> 2, n0 = (zz & 3) * 16;
    int k0 = kc * 64;
    const float* Asrc = (st & 1) ? hid : (ws + WS_S);
    const float* W = (st == 0) ? Wgvs : (st == 1) ? Wghs : (st == 2) ? Wgvc : Wghc;
    for (int i = tid; i < 1024; i += 256) {
      int nn = i >> 6, kk = i & 63;
      aT[kk * 20 + nn] = Asrc[(n0 + nn) * 512 + k0 + kk];
    }
    __syncthreads();
    float acc[16];
#pragma unroll
    for (int j = 0; j < 16; ++j) acc[j] = 0.0f;
#pragma unroll 4
    for (int kk = 0; kk < 64; ++kk) {
      float w = W[(k0 + kk) * 512 + c];
      const float4* a4 = (const float4*)&aT[kk * 20];
#pragma unroll
      for (int q = 0; q < 4; ++q) {
        float4 a = a4[q];
        acc[q * 4 + 0] += a.x * w;
        acc[q * 4 + 1] += a.y * w;
        acc[q * 4 + 2] += a.z * w;
        acc[q * 4 + 3] += a.w * w;
      }
    }
    float* C = ws + WS_GSPS + (st * 8 + kc) * 32768;
#pragma unroll
    for (int j = 0; j < 16; ++j) C[(n0 + j) * 512 + c] = acc[j];
  } else {
    int bidx = bid - 768;               // 0..127
    int n = bidx & 63, half = bidx >> 6;
    int k2 = tid & 63, w = tid >> 6;
    int kc = half * 4 + w;
    const float* hrow = hid + n * H;
    const float* srow = ws + WS_S + n * H;
    float a1 = 0.0f, a2 = 0.0f;
#pragma unroll 4
    for (int kk = 0; kk < 64; ++kk) {
      int k = kc * 64 + kk;
      if (k2 < NPIX) {
        a1 += hrow[k] * Wg[k * NPIX + k2];
        a2 += srow[k] * Ws_[k * NPIX + k2];
      }
    }
    if (k2 < NPIX) {
      ws[WS_P1 + (kc * 64 + n) * 64 + k2] = a1;
      ws[WS_P2 + (kc * 64 + n) * 64 + k2] = a2;
    }
  }
}

// attnM via bf16 MFMA, softmax fused. grid 1024 = (16 kc)x(64 n).
__global__ __launch_bounds__(256) void k_attnM(const float* __restrict__ V,
    const float* __restrict__ Wv, float* __restrict__ ws) {
  __shared__ __align__(16) short al[64 * 136];
  __shared__ __align__(16) short bl[64 * 136];
  __shared__ float red[8];
  int tid = threadIdx.x, bid = blockIdx.x;
  int kc = bid >> 6, n = bid & 63, b = n >> 3;
  int c0 = kc * 128;
  const float* cr = ws + WS_A0 + n * CDIM;
  const float* Vb = V + b * NPIX * CDIM + c0;
  int lane = tid & 63, w = tid >> 6;
  float v[8];
  float vmax = -1e30f;
#pragma unroll
  for (int i = 0; i < 8; ++i) { v[i] = cr[tid + i * 256]; vmax = fmaxf(vmax, v[i]); }
  for (int off = 32; off; off >>= 1) vmax = fmaxf(vmax, __shfl_xor(vmax, off));
  if (lane == 0) red[w] = vmax;
  __syncthreads();
  float m = fmaxf(fmaxf(red[0], red[1]), fmaxf(red[2], red[3]));
  float ss = 0.0f;
#pragma unroll
  for (int i = 0; i < 8; ++i) ss += __expf(v[i] - m);
  for (int off = 32; off; off >>= 1) ss += __shfl_xor(ss, off);
  if (lane == 0) red[4 + w] = ss;
  __syncthreads();
  float inv = rcp_fast(red[4] + red[5] + red[6] + red[7]);
  {
    int cc = tid & 127;
    float a0c = __expf(cr[c0 + cc] - m) * inv;
    for (int k = tid >> 7; k < NPIX; k += 2)
      al[k * 136 + cc] = f2bf(a0c * Vb[k * CDIM + cc]);
  }
  for (int idx = tid; idx < 128 * 64; idx += 256) {
    int cc = idx >> 6, r = idx & 63;
    if (r < NPIX) bl[r * 136 + cc] = f2bf(Wv[(c0 + cc) * NPIX + r]);
  }
  __syncthreads();
  if (tid < NPIX) {
    float cch = 0.0f;
    const unsigned short* ar = (const unsigned short*)(al + tid * 136);
#pragma unroll 8
    for (int cc = 0; cc < 128; ++cc) cch += bf2f(ar[cc]);
    ws[WS_CCH + (kc * 64 + n) * 52 + tid] = cch * (1.0f / CDIM);
  }
  int qm = lane >> 4, mr = lane & 15;
  floatx4 acc[4];
#pragma unroll
  for (int i = 0; i < 4; ++i) acc[i] = (floatx4){0.f, 0.f, 0.f, 0.f};
#pragma unroll
  for (int ks = 0; ks < 4; ++ks) {
    int cb = ks * 32 + qm * 8;
    short8 bf = *(const short8*)&bl[(w * 16 + mr) * 136 + cb];
#pragma unroll
    for (int i = 0; i < 4; ++i) {
      short8 af = *(const short8*)&al[(i * 16 + mr) * 136 + cb];
      acc[i] = __builtin_amdgcn_mfma_f32_16x16x32_bf16(af, bf, acc[i], 0, 0, 0);
    }
  }
  __syncthreads();
  float* ml = (float*)al;
  int k2 = w * 16 + mr;
  if (k2 < NPIX) {
#pragma unroll
    for (int i = 0; i < 4; ++i) {
#pragma unroll
      for (int r = 0; r < 4; ++r) {
        int kp = i * 16 + qm * 4 + r;
        if (kp < NPIX) ml[k2 * 49 + kp] = acc[i][r];
      }
    }
  }
  __syncthreads();
  float* Mp = ws + WS_MS + kc * 153664 + n * 2401;
  for (int idx = tid; idx < 2401; idx += 256) Mp[idx] = ml[idx];
}

// reduce the 16 M slabs -> MF[n][2401] ; grid (10, 64)
__global__ __launch_bounds__(256) void k_redM(float* __restrict__ ws) {
  int n = blockIdx.y;
  int i = blockIdx.x * 256 + threadIdx.x;
  if (i < 2401) {
    float m = 0.0f;
#pragma unroll
    for (int s = 0; s < 16; ++s) m += ws[WS_MS + s * 153664 + n * 2401 + i];
    ws[WS_MF + n * 2401 + i] = m;
  }
}

// zt: reduce P1/P2; z from single MF slab; alpha, beta
__global__ __launch_bounds__(256) void k_zt(const float* __restrict__ Wh,
    float* __restrict__ ws, float* __restrict__ out) {
  __shared__ float gl[NPIX], cl[NPIX], whl[64];
  __shared__ float zbuf[4][64];
  int n = blockIdx.x, tid = threadIdx.x;
  if (tid < NPIX) {
    float s1 = 0.0f, s2 = 0.0f;
#pragma unroll
    for (int kc = 0; kc < 8; ++kc) {
      s1 += ws[WS_P1 + (kc * 64 + n) * 64 + tid];
      s2 += ws[WS_P2 + (kc * 64 + n) * 64 + tid];
    }
    gl[tid] = s1;
    cl[tid] = s1 + s2;
    whl[tid] = Wh[tid];
  }
  __syncthreads();
  int k = tid & 63, g = tid >> 6;
  float zp = 0.0f;
  if (k < NPIX) {
    int k2e = (g == 3) ? NPIX : (g * 13 + 13);
    const float* Mz = ws + WS_MF + n * 2401;
    for (int k2 = g * 13; k2 < k2e; ++k2) {
      float m = Mz[k2 * 49 + k];
      zp += tanh_f(tanh_f(m + gl[k2])) * whl[k2];
    }
  }
  zbuf[g][k] = zp;
  __syncthreads();
  if (tid < 64) {
    int lane = tid;
    float z = zbuf[0][lane] + zbuf[1][lane] + zbuf[2][lane] + zbuf[3][lane];
    float zm = (lane < NPIX) ? z : -1e30f;
    float m1 = zm;
    for (int off = 32; off; off >>= 1) m1 = fmaxf(m1, __shfl_xor(m1, off));
    float e = (lane < NPIX) ? __expf(z - m1) : 0.0f;
    float S1 = e;
    for (int off = 32; off; off >>= 1) S1 += __shfl_xor(S1, off);
    if (lane < NPIX) out[OUT_ALPHA + n * NPIX + lane] = e * rcp_fast(S1);
    float vz = (lane < NPIX) ? tanh_f(cl[lane]) * whl[lane] : 0.0f;
    for (int off = 32; off; off >>= 1) vz += __shfl_xor(vz, off);
    if (lane == 0) {
      float ze = vz;
      float m2 = fmaxf(m1, ze);
      float S2 = S1 * __expf(m1 - m2) + __expf(ze - m2);
      out[OUT_BETA + n] = __expf(ze - m2) * rcp_fast(S2);
    }
  }
}

// c_spatial^T[d][n] = sum_k alpha_t[n][k] * V[b][k][d]
__global__ __launch_bounds__(256) void k_cspatial(const float* __restrict__ V,
    const float* __restrict__ out, float* __restrict__ ws) {
  __shared__ float al[NPIX];
  int bid = blockIdx.x, tid = threadIdx.x;
  int n = bid & 63, b = n >> 3;
  int d = (bid >> 6) * 256 + tid;
  if (tid < NPIX) al[tid] = out[OUT_ALPHA + n * NPIX + tid];
  __syncthreads();
  float s = 0.0f;
#pragma unroll 7
  for (int k = 0; k < NPIX; ++k) s += al[k] * V[b * NPIX * CDIM + k * CDIM + d];
  ws[WS_CSPT + d * 64 + n] = s;
}

// spat GEMMs (A already transposed in CSPT) -> WS_GSPS slabs 32..63 ; grid (2,8,16)
__global__ __launch_bounds__(256) void k_gemm_spat(const float* __restrict__ Wspat,
    float* __restrict__ ws) {
  int c = blockIdx.x * 256 + threadIdx.x;
  int kc = blockIdx.y;
  int z = blockIdx.z;
  int st = 4 + (z >> 2), n0 = (z & 3) * 16;
  int q = st - 4;
  const float* A = ws + WS_CSPT + q * 32768;
  const float* W = Wspat + q * 262144;
  int k0 = kc * 64;
  float acc[16];
#pragma unroll
  for (int j = 0; j < 16; ++j) acc[j] = 0.0f;
#pragma unroll 4
  for (int kk = 0; kk < 64; ++kk) {
    int k = k0 + kk;
    float w = W[k * 512 + c];
    const float4* A4 = (const float4*)(A + k * 64 + n0);
#pragma unroll
    for (int q2 = 0; q2 < 4; ++q2) {
      float4 a = A4[q2];
      acc[q2 * 4 + 0] += a.x * w;
      acc[q2 * 4 + 1] += a.y * w;
      acc[q2 * 4 + 2] += a.z * w;
      acc[q2 * 4 + 3] += a.w * w;
    }
  }
  float* C = ws + WS_GSPS + (st * 8 + kc) * 32768;
#pragma unroll
  for (int j = 0; j < 16; ++j) C[(n0 + j) * 512 + c] = acc[j];
}

// chat[n][c] = sigmoid(GA1)*SPAT + sigmoid(GA2)*(cchan@Wchan) + h -> bf16 [n][512]
__global__ __launch_bounds__(256) void k_chat(const float* __restrict__ hid,
    const float* __restrict__ Wchan, float* __restrict__ ws) {
  __shared__ float cl[NPIX];
  int tid = threadIdx.x, n = blockIdx.y;
  int c = blockIdx.x * 256 + tid;
  if (tid < NPIX) {
    float s = 0.0f;
#pragma unroll
    for (int kc = 0; kc < 16; ++kc) s += ws[WS_CCH + (kc * 64 + n) * 52 + tid];
    cl[tid] = s;
  }
  __syncthreads();
  float acc = 0.0f;
#pragma unroll 7
  for (int k = 0; k < NPIX; ++k) acc += cl[k] * Wchan[k * H + c];
  int idx = n * H + c;
  float ga1 = 0.0f, ga2 = 0.0f, spat = 0.0f;
#pragma unroll
  for (int s = 0; s < 16; ++s)  ga1 += ws[WS_GSPS + s * 32768 + idx];
#pragma unroll
  for (int s = 16; s < 32; ++s) ga2 += ws[WS_GSPS + s * 32768 + idx];
#pragma unroll
  for (int s = 32; s < 64; ++s) spat += ws[WS_GSPS + s * 32768 + idx];
  float chat = sigmoid_f(ga1) * spat + sigmoid_f(ga2) * acc + hid[idx];
  ((short*)(ws + WS_CHT))[idx] = f2bf(chat);
}

// scores via bf16 MFMA: grid (157 cb, 4 kc). Block: 64n x 64c tile over K=128.
// B staged LDS bf16 [c][k]; A fragments from global CHB (L2-hot 64KB).
__global__ __launch_bounds__(256) void k_gemm_scores(const float* __restrict__ Wmlp,
    float* __restrict__ ws) {
  __shared__ __align__(16) short bl[64 * 136];
  int tid = threadIdx.x;
  int cb = blockIdx.x, kc = blockIdx.y;
  int c0 = cb * 64, k0 = kc * 128;
  const short* CHB = (const short*)(ws + WS_CHT);
  int lane = tid & 63, w = tid >> 6;
  int mr = lane & 15, kg = lane >> 4;
  for (int i = tid; i < 128 * 64; i += 256) {
    int kk = i >> 6, cc = i & 63;
    int c = c0 + cc;
    float v = (c < VOCAB) ? Wmlp[(k0 + kk) * VOCAB + c] : 0.0f;
    bl[cc * 136 + kk] = f2bf(v);
  }
  __syncthreads();
  floatx4 acc[4];
#pragma unroll
  for (int i = 0; i < 4; ++i) acc[i] = (floatx4){0.f, 0.f, 0.f, 0.f};
#pragma unroll
  for (int ks = 0; ks < 4; ++ks) {
    short8 af = *(const short8*)&CHB[(w * 16 + mr) * 512 + k0 + ks * 32 + kg * 8];
#pragma unroll
    for (int ct = 0; ct < 4; ++ct) {
      short8 bf = *(const short8*)&bl[(ct * 16 + mr) * 136 + ks * 32 + kg * 8];
      acc[ct] = __builtin_amdgcn_mfma_f32_16x16x32_bf16(af, bf, acc[ct], 0, 0, 0);
    }
  }
  float* slab = ws + WS_SCS + kc * 640000;
#pragma unroll
  for (int ct = 0; ct < 4; ++ct) {
    int c = c0 + ct * 16 + mr;
    if (c < VOCAB) {
#pragma unroll
      for (int r = 0; r < 4; ++r) {
        int n = w * 16 + kg * 4 + r;
        slab[n * VOCAB + c] = acc[ct][r];
      }
    }
  }
}

// out[n][c] = bmlp[c] + sum of 4 score slabs ; float4 ; grid (10, 64)
__global__ __launch_bounds__(256) void k_red_scores(const float* __restrict__ bmlp,
    float* __restrict__ ws, float* __restrict__ out) {
  int c4 = blockIdx.x * 256 + threadIdx.x, n = blockIdx.y;
  if (c4 >= VOCAB / 4) return;
  const float4* b4 = (const float4*)bmlp;
  float4 v = b4[c4];
#pragma unroll
  for (int s = 0; s < 4; ++s) {
    float4 p = ((const float4*)(ws + WS_SCS + s * 640000 + n * VOCAB))[c4];
    v.x += p.x; v.y += p.y; v.z += p.z; v.w += p.w;
  }
  ((float4*)(out + n * VOCAB))[c4] = v;
}

extern "C" void kernel_launch(void* const* d_in, const int* in_sizes, int n_in,
                              void* d_out, int out_size, void* d_ws, size_t ws_size,
                              hipStream_t stream) {
  const float* x     = (const float*)d_in[0];
  const float* hid   = (const float*)d_in[1];
  const float* cells = (const float*)d_in[2];
  const float* V     = (const float*)d_in[3];
  const float* Wsx   = (const float*)d_in[4];
  const float* Wsh   = (const float*)d_in[5];
  const float* Wv    = (const float*)d_in[6];
  const float* Wg    = (const float*)d_in[7];
  const float* Ws_   = (const float*)d_in[8];
  const float* Wh    = (const float*)d_in[9];
  const float* Wfeat = (const float*)d_in[10];
  const float* Wcxt  = (const float*)d_in[11];
  const float* Wg2   = (const float*)d_in[12];
  const float* Wspat = (const float*)d_in[13];
  const float* Wchan = (const float*)d_in[14];
  const float* Wgvs  = (const float*)d_in[15];
  const float* Wgvc  = (const float*)d_in[16];
  const float* Wghs  = (const float*)d_in[17];
  const float* Wghc  = (const float*)d_in[18];
  const float* Wmlp  = (const float*)d_in[19];
  const float* bmlp  = (const float*)d_in[20];
  float* ws  = (float*)d_ws;
  float* out = (float*)d_out;

  hipLaunchKernelGGL(k_sg2, dim3(448), dim3(256), 0, stream, Wsx, Wsh, Wg2, x, hid, V, ws);
  hipLaunchKernelGGL(k_act_s, dim3(128), dim3(256), 0, stream, cells, ws);
  hipLaunchKernelGGL(k_mid, dim3(896), dim3(256), 0, stream, Wfeat, Wcxt, Wgvs, Wghs, Wgvc, Wghc, hid, Wg, Ws_, ws);
  hipLaunchKernelGGL(k_attnM, dim3(1024), dim3(256), 0, stream, V, Wv, ws);
  hipLaunchKernelGGL(k_redM, dim3(10, 64), dim3(256), 0, stream, ws);
  hipLaunchKernelGGL(k_zt, dim3(64), dim3(256), 0, stream, Wh, ws, out);
  hipLaunchKernelGGL(k_cspatial, dim3(512), dim3(256), 0, stream, V, out, ws);
  hipLaunchKernelGGL(k_gemm_spat, dim3(2, 8, 16), dim3(256), 0, stream, Wspat, ws);
  hipLaunchKernelGGL(k_chat, dim3(2, 64), dim3(256), 0, stream, hid, Wchan, ws);
  hipLaunchKernelGGL(k_gemm_scores, dim3(157, 4), dim3(256), 0, stream, Wmlp, ws);
  hipLaunchKernelGGL(k_red_scores, dim3(10, 64), dim3(256), 0, stream, bmlp, ws, out);
}